// Round 5
// baseline (377.376 us; speedup 1.0000x reference)
//
#include <hip/hip_runtime.h>
#include <hip/hip_bf16.h>

// Problem constants
#define B_   32
#define S_   512
#define NB_  20
#define EMB_ 128
#define VOC_ 40000

typedef float f32x4 __attribute__((ext_vector_type(4)));
typedef _Float16 f16x8 __attribute__((ext_vector_type(8)));
typedef __fp16 fp16x2 __attribute__((ext_vector_type(2)));

union FragH { uint4 u; f16x8 h; };
union H2 { fp16x2 h; unsigned u; };

__device__ __forceinline__ unsigned pk2(float a, float b){
  H2 t; t.h = __builtin_amdgcn_cvt_pkrtz(a, b);
  return t.u;
}
__device__ __forceinline__ unsigned short f2h(float x){
  _Float16 h = (_Float16)x;   // RNE
  return __builtin_bit_cast(unsigned short, h);
}
__device__ __forceinline__ float h2f(unsigned short s){
  return (float)__builtin_bit_cast(_Float16, s);
}
__device__ __forceinline__ float tanh_fast(float x){
  float xx = fminf(fmaxf(x, -15.f), 15.f);
  float e = __expf(2.f*xx);
  return (e-1.f)/(e+1.f);
}

// ---------------------------------------------------------------------------
// Prep: u, qc=u@C, tf=u@F, uh=u@H, kb=emb[keys]@Bm (fp32),
// plus fp16 B-operand fragments of A (K=128) and [D;E] (K=256).
// B-frag: chunk=((nt*KC+kc)*64+lane): n=nt*16+(lane&15), k=kc*32+(lane>>4)*8+j
// ---------------------------------------------------------------------------
__global__ __launch_bounds__(128) void prep_kernel(
    const int* __restrict__ queries, const int* __restrict__ keys,
    const float* __restrict__ emb, const float* __restrict__ mmask,
    const float* __restrict__ A, const float* __restrict__ Bm,
    const float* __restrict__ C, const float* __restrict__ D,
    const float* __restrict__ E, const float* __restrict__ F,
    const float* __restrict__ H,
    float* __restrict__ qc_w, float* __restrict__ tf_w,
    float* __restrict__ uh_w, float* __restrict__ kb_w,
    unsigned short* __restrict__ afrag, unsigned short* __restrict__ w2frag)
{
  int bid = blockIdx.x, tid = threadIdx.x;
  if (bid < 32) {
    __shared__ float ulds[128];
    int b = bid;
    float s = 0.f;
    for (int q=0;q<NB_;q++){
      int tok = queries[b*NB_+q];
      s += emb[tok*128+tid]*mmask[q*128+tid];
    }
    ulds[tid] = s;
    __syncthreads();
    float sq=0.f, sf=0.f, sh=0.f;
    for (int e=0;e<128;e++){
      float uv = ulds[e];
      sq += uv*C[e*128+tid];
      sf += uv*F[e*128+tid];
      sh += uv*H[e*128+tid];
    }
    qc_w[b*128+tid]=sq; tf_w[b*128+tid]=sf; uh_w[b*128+tid]=sh;
  } else if (bid < 52) {
    __shared__ float ek[128];
    int n = bid-32;
    int tok = keys[n];
    ek[tid] = emb[tok*128+tid];
    __syncthreads();
    float s=0.f;
    for (int e=0;e<128;e++) s += ek[e]*Bm[e*128+tid];
    kb_w[n*128+tid] = s;
  } else if (bid < 60) {
    // A fragments: nt=8, kc=4 -> 2048 chunks fp16
    int a = bid-52;
    for (int cc=0;cc<2;cc++){
      int c = (a*128+tid)*2+cc;
      int lane = c&63, kc = (c>>6)&3, nt = c>>8;
      int n2 = nt*16 + (lane&15);
      int k0 = kc*32 + (lane>>4)*8;
      alignas(16) unsigned short t[8];
      #pragma unroll
      for (int j=0;j<8;j++) t[j] = f2h(A[(k0+j)*128+n2]);
      *(uint4*)(afrag + c*8) = *(const uint4*)t;
    }
  } else {
    // W2=[D;E] fragments: nt=8, kc=8 -> 4096 chunks fp16
    int wb = bid-60;
    for (int cc=0;cc<2;cc++){
      int c = (wb*128+tid)*2+cc;
      int lane = c&63, kc = (c>>6)&7, nt = c>>9;
      int n2 = nt*16 + (lane&15);
      int k0 = kc*32 + (lane>>4)*8;
      alignas(16) unsigned short t[8];
      #pragma unroll
      for (int j=0;j<8;j++){
        int k = k0+j;
        float x = (k<128) ? D[k*128+n2] : E[(k-128)*128+n2];
        t[j] = f2h(x);
      }
      *(uint4*)(w2frag + c*8) = *(const uint4*)t;
    }
  }
}

// ---------------------------------------------------------------------------
// K2a: 4 (b,s) pairs/block -> M=80 rows (row=p*20+n), K=128, N=128, fp16 MFMA.
// Swizzled LDS staging (conflict-free). Epilogue: align = sum_i v_i
// tanh(ia+kb+qc); softmax over n; tm = attn.mem, written as fp16.
// ---------------------------------------------------------------------------
__global__ __launch_bounds__(256) void k2a_kernel(
    const float* __restrict__ mem, const unsigned short* __restrict__ afrag,
    const float* __restrict__ kb_w, const float* __restrict__ qc_w,
    const float* __restrict__ vvec, unsigned short* __restrict__ tm16)
{
  __shared__ unsigned short mfr[5*4*64*8];   // 20KB fp16 tile
  __shared__ float alignP[4*80];
  __shared__ float aligns[80];
  __shared__ float attns[80];

  int g = blockIdx.x, tid = threadIdx.x;
  int b = g >> 7;   // 128 blocks per batch element

  // stage: 10240 contiguous floats -> fp16, swizzled frag layout
  const float4* gm = (const float4*)(mem) + (size_t)g*2560;
  #pragma unroll
  for (int it=0; it<10; ++it){
    int i4 = tid + it*256;
    float4 d = gm[i4];
    int e4 = i4*4;
    int row = e4 >> 7;          // 0..79
    int k = e4 & 127;
    int mt = row>>4, r = row&15;
    int kg = k>>5, s2 = (k>>3)&3;
    int slot = (s2<<4) | ((r ^ s2 ^ ((kg&1)<<2)) & 15);
    int chunk = (mt*4+kg)*64 + slot;
    *(uint2*)(mfr + chunk*8 + (k&7)) = make_uint2(pk2(d.x,d.y), pk2(d.z,d.w));
  }
  __syncthreads();

  int w = tid>>6, lane = tid&63;
  int lo16 = lane & 15, hi16 = lane >> 4;

  f32x4 acc[5][2];
  #pragma unroll
  for (int mt=0;mt<5;mt++){ acc[mt][0]=(f32x4)(0.f); acc[mt][1]=(f32x4)(0.f); }

  #pragma unroll
  for (int kc=0;kc<4;kc++){
    FragH b0, b1;
    b0.u = *(const uint4*)(afrag + ((size_t)((2*w)*4+kc)*64 + lane)*8);
    b1.u = *(const uint4*)(afrag + ((size_t)((2*w+1)*4+kc)*64 + lane)*8);
    int slot = (hi16<<4) | ((lo16 ^ hi16 ^ ((kc&1)<<2)) & 15);
    #pragma unroll
    for (int mt=0;mt<5;mt++){
      FragH a;
      a.u = *(const uint4*)(mfr + ((mt*4+kc)*64 + slot)*8);
      acc[mt][0] = __builtin_amdgcn_mfma_f32_16x16x32_f16(a.h, b0.h, acc[mt][0], 0,0,0);
      acc[mt][1] = __builtin_amdgcn_mfma_f32_16x16x32_f16(a.h, b1.h, acc[mt][1], 0,0,0);
    }
  }

  // epilogue: align[row] = sum_i v_i * tanh(ia + kb[n,i] + qc[b,i])
  #pragma unroll
  for (int mt=0;mt<5;mt++){
    #pragma unroll
    for (int r=0;r<4;r++){
      unsigned row = mt*16 + hi16*4 + r;
      unsigned p = row/20u;
      unsigned n = row - p*20u;
      float part = 0.f;
      #pragma unroll
      for (int t2=0;t2<2;t2++){
        int col = (2*w+t2)*16 + lo16;
        float z = acc[mt][t2][r] + kb_w[n*128+col] + qc_w[b*128+col];
        part += vvec[col]*tanh_fast(z);
      }
      part += __shfl_xor(part, 1);
      part += __shfl_xor(part, 2);
      part += __shfl_xor(part, 4);
      part += __shfl_xor(part, 8);
      if (lo16 == 0) alignP[w*80+row] = part;
    }
  }
  __syncthreads();
  if (tid < 80){
    aligns[tid] = alignP[tid] + alignP[80+tid] + alignP[160+tid] + alignP[240+tid];
  }
  __syncthreads();
  if (tid < 4){
    float mx = -1e30f;
    for (int n=0;n<NB_;n++) mx = fmaxf(mx, aligns[tid*NB_+n]);
    float s = 0.f;
    for (int n=0;n<NB_;n++){ float e = __expf(aligns[tid*NB_+n]-mx); attns[tid*NB_+n]=e; s+=e; }
    float inv = 1.f/s;
    for (int n=0;n<NB_;n++) attns[tid*NB_+n] *= inv;
  }
  __syncthreads();

  // tm[p][e] = sum_n attn * mem (fp16 from swizzled LDS), write fp16
  if (tid < 128){
    int p2 = tid>>5, e0 = (tid&31)*4;
    int kg = e0>>5, s2 = (e0>>3)&3;
    float4 o = make_float4(0.f,0.f,0.f,0.f);
    #pragma unroll
    for (int n=0;n<NB_;n++){
      int row = p2*NB_+n;
      float a = attns[row];
      int mt = row>>4, r = row&15;
      int slot = (s2<<4) | ((r ^ s2 ^ ((kg&1)<<2)) & 15);
      int chunk = (mt*4+kg)*64 + slot;
      uint2 pk = *(const uint2*)(mfr + chunk*8 + (e0&7));
      H2 q0, q1; q0.u = pk.x; q1.u = pk.y;
      o.x += a*(float)q0.h[0];
      o.y += a*(float)q0.h[1];
      o.z += a*(float)q1.h[0];
      o.w += a*(float)q1.h[1];
    }
    *(uint2*)(tm16 + ((size_t)g*4+p2)*128 + e0) = make_uint2(pk2(o.x,o.y), pk2(o.z,o.w));
  }
}

// ---------------------------------------------------------------------------
// K2b: 16 pairs/block, A=[tm16|stories] (K=256) fp16, B=[D;E] fp16.
// Coalesced staging: linear chunk reads, XOR-swizzled LDS frag writes.
//   frag element (row p, k): kc=k>>5, s2=(k>>3)&3; slot = s2*16+((p^(s2<<2))&15)
// talign = (mask!=0) ? mask*sum_i w_i tanh(td+te+tf) : -inf
// ---------------------------------------------------------------------------
__global__ __launch_bounds__(256) void k2b_kernel(
    const unsigned short* __restrict__ tm16, const float* __restrict__ stories,
    const unsigned short* __restrict__ w2frag, const float* __restrict__ tf_w,
    const float* __restrict__ wvec, const float* __restrict__ smask,
    float* __restrict__ talign_w)
{
  __shared__ unsigned short afr[512*8];  // 8KB
  __shared__ float partial[4*16];
  int gb = blockIdx.x, tid = threadIdx.x;
  int flat0 = gb*16;
  int b = flat0 >> 9;

  // stage 512 chunks: cid<256 from tm16 (fp16 direct), cid>=256 from stories
  #pragma unroll
  for (int it=0;it<2;it++){
    int cid = tid + it*256;
    int row = (cid & 255) >> 4;
    int kpart = (cid & 15) * 8;
    int kc = kpart >> 5, s2 = (kpart >> 3) & 3;
    uint4 val;
    if (cid < 256){
      val = *(const uint4*)(tm16 + ((size_t)(flat0+row))*128 + kpart);
    } else {
      const float* src = stories + ((size_t)(flat0+row))*128 + kpart;
      float4 a0 = *(const float4*)src;
      float4 a1 = *(const float4*)(src+4);
      val.x = pk2(a0.x,a0.y); val.y = pk2(a0.z,a0.w);
      val.z = pk2(a1.x,a1.y); val.w = pk2(a1.z,a1.w);
      kc += 4;
    }
    int slot = s2*16 + ((row ^ (s2<<2)) & 15);
    *(uint4*)(afr + (kc*64 + slot)*8) = val;
  }
  __syncthreads();

  int w = tid>>6, lane = tid&63;
  int lo = lane&15, hi = lane>>4;
  int rslot = hi*16 + ((lo ^ (hi<<2)) & 15);
  f32x4 acc0 = (f32x4)(0.f), acc1 = (f32x4)(0.f);

  #pragma unroll
  for (int kc=0;kc<8;kc++){
    FragH af, b0, b1;
    af.u = *(const uint4*)(afr + (kc*64+rslot)*8);
    b0.u = *(const uint4*)(w2frag + ((size_t)((2*w)*8+kc)*64+lane)*8);
    b1.u = *(const uint4*)(w2frag + ((size_t)((2*w+1)*8+kc)*64+lane)*8);
    acc0 = __builtin_amdgcn_mfma_f32_16x16x32_f16(af.h, b0.h, acc0, 0,0,0);
    acc1 = __builtin_amdgcn_mfma_f32_16x16x32_f16(af.h, b1.h, acc1, 0,0,0);
  }

  #pragma unroll
  for (int r=0;r<4;r++){
    int prow = hi*4+r;
    float part = 0.f;
    {
      int i0 = (2*w)*16+lo;
      part += wvec[i0]*tanh_fast(acc0[r] + tf_w[b*128+i0]);
      int i1 = (2*w+1)*16+lo;
      part += wvec[i1]*tanh_fast(acc1[r] + tf_w[b*128+i1]);
    }
    part += __shfl_xor(part,1);
    part += __shfl_xor(part,2);
    part += __shfl_xor(part,4);
    part += __shfl_xor(part,8);
    if (lo==0) partial[w*16+prow] = part;
  }
  __syncthreads();
  if (tid<16){
    float ta = partial[tid]+partial[16+tid]+partial[32+tid]+partial[48+tid];
    int flat = flat0+tid;
    float m = smask[flat];
    talign_w[flat] = (m != 0.0f) ? ta*m : -INFINITY;
  }
}

// ---------------------------------------------------------------------------
// K3 (merged): softmax over S=512, o = sum_s attn*tm16, ov = o + uh
// ---------------------------------------------------------------------------
__global__ __launch_bounds__(256) void k3_kernel(
    const float* __restrict__ talign_w, const unsigned short* __restrict__ tm16,
    const float* __restrict__ uh_w, float* __restrict__ ov_w)
{
  __shared__ float attn[512];
  __shared__ float red[256];
  int b = blockIdx.x, tid = threadIdx.x;
  float v0 = talign_w[b*512+tid];
  float v1 = talign_w[b*512+256+tid];
  red[tid] = fmaxf(v0,v1);
  __syncthreads();
  for (int s=128;s>0;s>>=1){ if (tid<s) red[tid]=fmaxf(red[tid],red[tid+s]); __syncthreads(); }
  float M = red[0];
  __syncthreads();
  float e0 = __expf(v0-M), e1 = __expf(v1-M);
  red[tid] = e0+e1;
  __syncthreads();
  for (int s=128;s>0;s>>=1){ if (tid<s) red[tid]+=red[tid+s]; __syncthreads(); }
  float invZ = 1.f/red[0];
  attn[tid] = e0*invZ;
  attn[256+tid] = e1*invZ;
  __syncthreads();

  int e = tid&127, h = tid>>7;
  const unsigned short* tmb = tm16 + ((size_t)b*512 + h*256)*128 + e;
  float a = 0.f;
  #pragma unroll 4
  for (int i=0;i<256;i++){
    a += attn[h*256+i]*h2f(tmb[(size_t)i*128]);
  }
  red[tid] = a;
  __syncthreads();
  if (tid<128) ov_w[b*128+tid] = red[tid]+red[128+tid]+uh_w[b*128+tid];
}

// ---------------------------------------------------------------------------
// K4: logits[b][j] = sum_e ov[b][e]*R[e][j]; 625 blocks, j-tile 64, 4 b-groups
// ---------------------------------------------------------------------------
__global__ __launch_bounds__(256) void k4_kernel(
    const float* __restrict__ ov_w, const float* __restrict__ R,
    float* __restrict__ out)
{
  int tid = threadIdx.x;
  int j = blockIdx.x*64 + (tid&63);
  int bh = tid>>6;                 // 0..3 -> b = bh*8 + bb
  const float* ovb = ov_w + bh*8*128;
  float acc[8];
  #pragma unroll
  for (int bb=0;bb<8;bb++) acc[bb]=0.f;
  for (int e=0;e<128;e+=4){
    float r0 = R[(size_t)(e+0)*VOC_ + j];
    float r1 = R[(size_t)(e+1)*VOC_ + j];
    float r2 = R[(size_t)(e+2)*VOC_ + j];
    float r3 = R[(size_t)(e+3)*VOC_ + j];
    #pragma unroll
    for (int bb=0;bb<8;bb++){
      acc[bb] += ovb[bb*128+e+0]*r0 + ovb[bb*128+e+1]*r1
               + ovb[bb*128+e+2]*r2 + ovb[bb*128+e+3]*r3;
    }
  }
  #pragma unroll
  for (int bb=0;bb<8;bb++) out[(size_t)(bh*8+bb)*VOC_ + j] = acc[bb];
}

// ---------------------------------------------------------------------------
extern "C" void kernel_launch(void* const* d_in, const int* in_sizes, int n_in,
                              void* d_out, int out_size, void* d_ws, size_t ws_size,
                              hipStream_t stream)
{
  const float* mem    = (const float*)d_in[0];
  const float* stories= (const float*)d_in[1];
  const float* smask  = (const float*)d_in[2];
  const int*   queries= (const int*)d_in[3];
  const int*   keys   = (const int*)d_in[4];
  const float* emb    = (const float*)d_in[5];
  const float* mmask  = (const float*)d_in[6];
  const float* A      = (const float*)d_in[7];
  const float* Bm     = (const float*)d_in[8];
  const float* C      = (const float*)d_in[9];
  const float* vvec   = (const float*)d_in[10];
  const float* D      = (const float*)d_in[11];
  const float* E      = (const float*)d_in[12];
  const float* F      = (const float*)d_in[13];
  const float* wvec   = (const float*)d_in[14];
  const float* H      = (const float*)d_in[15];
  const float* R      = (const float*)d_in[16];
  float* out = (float*)d_out;

  char* ws = (char*)d_ws;
  float* qc_w             = (float*)(ws + 0);          // 16384
  float* tf_w             = (float*)(ws + 16384);      // 16384
  float* uh_w             = (float*)(ws + 32768);      // 16384
  float* kb_w             = (float*)(ws + 49152);      // 10240
  unsigned short* afrag   = (unsigned short*)(ws + 60416);   // 32768
  unsigned short* w2frag  = (unsigned short*)(ws + 93184);   // 65536
  unsigned short* tm16    = (unsigned short*)(ws + 158720);  // 4194304
  float* talign_w         = (float*)(ws + 4353024);    // 65536
  float* ov_w             = (float*)(ws + 4418560);    // 16384

  prep_kernel<<<76,128,0,stream>>>(queries, keys, emb, mmask, A, Bm, C, D, E, F, H,
                                   qc_w, tf_w, uh_w, kb_w, afrag, w2frag);
  k2a_kernel<<<4096,256,0,stream>>>(mem, afrag, kb_w, qc_w, vvec, tm16);
  k2b_kernel<<<1024,256,0,stream>>>(tm16, stories, w2frag, tf_w, wvec, smask, talign_w);
  k3_kernel<<<32,256,0,stream>>>(talign_w, tm16, uh_w, ov_w);
  k4_kernel<<<625,256,0,stream>>>(ov_w, R, out);
}